// Round 1
// baseline (2502.203 us; speedup 1.0000x reference)
//
#include <hip/hip_runtime.h>
#include <cstdint>

#define BB 2048
#define NN 128
#define DD 128
#define CHUNK 1024
#define SW 36

// ---------------- threefry2x32 (JAX-exact) ----------------
__device__ __forceinline__ void tf_round(uint32_t& x0, uint32_t& x1, int r) {
  x0 += x1; x1 = (x1 << r) | (x1 >> (32 - r)); x1 ^= x0;
}

__device__ __forceinline__ uint2 threefry(uint32_t k0, uint32_t k1, uint32_t x0, uint32_t x1) {
  uint32_t k2 = k0 ^ k1 ^ 0x1BD11BDAu;
  x0 += k0; x1 += k1;
  tf_round(x0,x1,13); tf_round(x0,x1,15); tf_round(x0,x1,26); tf_round(x0,x1,6);
  x0 += k1; x1 += k2 + 1u;
  tf_round(x0,x1,17); tf_round(x0,x1,29); tf_round(x0,x1,16); tf_round(x0,x1,24);
  x0 += k2; x1 += k0 + 2u;
  tf_round(x0,x1,13); tf_round(x0,x1,15); tf_round(x0,x1,26); tf_round(x0,x1,6);
  x0 += k0; x1 += k1 + 3u;
  tf_round(x0,x1,17); tf_round(x0,x1,29); tf_round(x0,x1,16); tf_round(x0,x1,24);
  x0 += k1; x1 += k2 + 4u;
  tf_round(x0,x1,13); tf_round(x0,x1,15); tf_round(x0,x1,26); tf_round(x0,x1,6);
  x0 += k2; x1 += k0 + 5u;
  uint2 r; r.x = x0; r.y = x1; return r;
}

__device__ __forceinline__ float gumbel_from_bits(uint32_t bits) {
  const float TINY = 1.17549435e-38f;
  float u = __uint_as_float(0x3F800000u | (bits >> 9)) - 1.0f;   // [0,1)
  u = u + TINY;
  u = fmaxf(TINY, u);
  return -logf(-logf(u));   // libm logf: sampling-critical, do not weaken
}

// keys[i] = threefry((0,42),(0,i))
__global__ void k_keys(uint2* __restrict__ keys) {
  int i = threadIdx.x;
  if (i < NN) keys[i] = threefry(0u, 42u, 0u, (uint32_t)i);
}

// M = Wc2 @ Wq   (Wc rows 128..255 are the h_cur part)
__global__ void k_M(const float* __restrict__ Wc, const float* __restrict__ Wq,
                    float* __restrict__ M) {
  __shared__ __align__(16) float wrow[DD];
  int r = blockIdx.x, o = threadIdx.x;
  wrow[o] = Wc[(DD + r) * DD + o];
  __syncthreads();
  float acc = 0.f;
#pragma unroll 4
  for (int c = 0; c < DD; ++c) acc += wrow[c] * Wq[c * DD + o];
  M[r * DD + o] = acc;
}

// Qbase[b] = (graph[b]@Wc1 + bc) @ Wq + bq
__global__ void k_qbase(const float* __restrict__ graph, const float* __restrict__ Wc,
                        const float* __restrict__ bc, const float* __restrict__ Wq,
                        const float* __restrict__ bq, float* __restrict__ Qbase) {
  __shared__ __align__(16) float g[DD];
  __shared__ __align__(16) float c1[DD];
  int b = blockIdx.x, t = threadIdx.x;
  g[t] = graph[b * DD + t];
  __syncthreads();
  float acc = 0.f;
#pragma unroll 4
  for (int r = 0; r < DD; ++r) acc += g[r] * Wc[r * DD + t];
  c1[t] = acc + bc[t];
  __syncthreads();
  float acc2 = 0.f;
#pragma unroll 4
  for (int c = 0; c < DD; ++c) acc2 += c1[c] * Wq[c * DD + t];
  Qbase[b * DD + t] = acc2 + bq[t];
}

// K = h@Wk + bk ; QQ = h@M + Qbase[b]
// 64 rows/block, 512 threads, 4 rows x 4 cols x 2 mats per thread (32 acc).
// VGPR target <=128 -> 4 waves/SIMD (was 64 acc/thread -> 256 VGPR -> 2 waves/SIMD).
// As panel is XOR-swizzled (unpadded 64x32 put every a-read in one bank group).
// Per-element accumulation order over (kp,k4,kk) IDENTICAL to prior version.
__global__ __launch_bounds__(512, 4) void k_kqq(
    const float* __restrict__ h, const float* __restrict__ Wk, const float* __restrict__ bk,
    const float* __restrict__ Mm, const float* __restrict__ Qbase,
    float* __restrict__ Kc, float* __restrict__ QQc, int b0) {
  __shared__ __align__(16) float As[64 * 32];    // 8 KB, swizzled
  __shared__ __align__(16) float Wks[32 * DD];   // 16 KB
  __shared__ __align__(16) float Mms[32 * DD];   // 16 KB
  int tid = threadIdx.x;
  int grow0 = b0 * NN + blockIdx.x * 64;  // global flat row (b*N+n)
  int ty = tid >> 5, tx = tid & 31;       // ty 0..15 (4 rows each), tx 0..31 (4 cols each)
  float accK[4][4] = {{0}}, accQ[4][4] = {{0}};
  for (int kp = 0; kp < DD; kp += 32) {
    __syncthreads();
    {                                                 // h panel 64x32 (1 float4/thread)
      int r = tid >> 3, c4 = (tid & 7) * 4;
      int pc = c4 ^ ((r & 7) * 4);
      *(float4*)&As[r * 32 + pc] = *(const float4*)&h[(size_t)(grow0 + r) * DD + kp + c4];
    }
#pragma unroll
    for (int p = 0; p < 2; ++p) {                     // weight panels 32x128
      int t = tid + p * 512;
      int r = t >> 5, c4 = (t & 31) * 4;
      *(float4*)&Wks[r * DD + c4] = *(const float4*)&Wk[(size_t)(kp + r) * DD + c4];
      *(float4*)&Mms[r * DD + c4] = *(const float4*)&Mm[(size_t)(kp + r) * DD + c4];
    }
    __syncthreads();
#pragma unroll
    for (int k4 = 0; k4 < 32; k4 += 4) {
      float4 a4[4];
#pragma unroll
      for (int i = 0; i < 4; ++i) {
        int row = ty * 4 + i;
        a4[i] = *(const float4*)&As[row * 32 + (k4 ^ ((row & 7) * 4))];
      }
#pragma unroll
      for (int kk = 0; kk < 4; ++kk) {
        float4 w = *(const float4*)&Wks[(k4 + kk) * DD + tx * 4];
        float4 m = *(const float4*)&Mms[(k4 + kk) * DD + tx * 4];
#pragma unroll
        for (int i = 0; i < 4; ++i) {
          float a = ((const float*)&a4[i])[kk];
          accK[i][0] += a * w.x; accK[i][1] += a * w.y; accK[i][2] += a * w.z; accK[i][3] += a * w.w;
          accQ[i][0] += a * m.x; accQ[i][1] += a * m.y; accQ[i][2] += a * m.z; accQ[i][3] += a * m.w;
        }
      }
    }
  }
  float4 bk4 = *(const float4*)&bk[tx * 4];
#pragma unroll
  for (int i = 0; i < 4; ++i) {
    int grow = grow0 + ty * 4 + i;
    int b = grow >> 7;
    int lrow = grow - b0 * NN;
    float4 qb = *(const float4*)&Qbase[b * DD + tx * 4];
    float4 ok, oq;
    ok.x = accK[i][0] + bk4.x; ok.y = accK[i][1] + bk4.y;
    ok.z = accK[i][2] + bk4.z; ok.w = accK[i][3] + bk4.w;
    oq.x = accQ[i][0] + qb.x;  oq.y = accQ[i][1] + qb.y;
    oq.z = accQ[i][2] + qb.z;  oq.w = accQ[i][3] + qb.w;
    *(float4*)&Kc[lrow * DD + tx * 4] = ok;
    *(float4*)&QQc[lrow * DD + tx * 4] = oq;
  }
}

// T[b] = 10*tanh( QQ[b] @ K[b]^T / 32 )
// 512 threads, 4x8 per thread (32 acc) -> VGPR ~110, 4 waves/SIMD (was 64 acc -> 256 VGPR).
// Same 128x128 block tile, same LDS swizzle; per-element FMA order identical (bit-exact).
__global__ __launch_bounds__(512, 4) void k_score(
    const float* __restrict__ QQc, const float* __restrict__ Kc,
    float* __restrict__ T, int b0) {
  __shared__ __align__(16) float QQs[NN * SW];
  __shared__ __align__(16) float Ks[NN * SW];
  int bb = blockIdx.x;
  int tid = threadIdx.x;
  int ty = tid >> 4, tx = tid & 15;     // ty 0..31 (4 rows each), tx 0..15 (8 cols each)
  const float* QQb = QQc + (size_t)bb * NN * DD;
  const float* Kb  = Kc  + (size_t)bb * NN * DD;
  float acc[4][8] = {{0}};
  for (int kp = 0; kp < DD; kp += 32) {
#pragma unroll
    for (int p = 0; p < 2; ++p) {
      int idx = tid + p * 512;
      int row = idx >> 3, c4 = (idx & 7) * 4;
      int pc = c4 ^ (((row >> 3) & 7) * 4);
      *(float4*)&QQs[row * SW + pc] = *(const float4*)&QQb[row * DD + kp + c4];
      *(float4*)&Ks [row * SW + pc] = *(const float4*)&Kb [row * DD + kp + c4];
    }
    __syncthreads();
#pragma unroll
    for (int k4 = 0; k4 < 32; k4 += 4) {
      int ca = k4 ^ (((ty >> 1) & 7) * 4);
      int cb = k4 ^ ((tx & 7) * 4);
      float4 a[4], bv[8];
#pragma unroll
      for (int i = 0; i < 4; ++i) a[i]  = *(const float4*)&QQs[(ty * 4 + i) * SW + ca];
#pragma unroll
      for (int j = 0; j < 8; ++j) bv[j] = *(const float4*)&Ks [(tx * 8 + j) * SW + cb];
#pragma unroll
      for (int i = 0; i < 4; ++i)
#pragma unroll
        for (int j = 0; j < 8; ++j)
          acc[i][j] += a[i].x * bv[j].x + a[i].y * bv[j].y +
                       a[i].z * bv[j].z + a[i].w * bv[j].w;
    }
    __syncthreads();
  }
  int b = b0 + bb;
#pragma unroll
  for (int i = 0; i < 4; ++i) {
    int row = ty * 4 + i;
    float4 o0, o1;
    o0.x = 10.0f * tanhf(acc[i][0] * 0.03125f);
    o0.y = 10.0f * tanhf(acc[i][1] * 0.03125f);
    o0.z = 10.0f * tanhf(acc[i][2] * 0.03125f);
    o0.w = 10.0f * tanhf(acc[i][3] * 0.03125f);
    o1.x = 10.0f * tanhf(acc[i][4] * 0.03125f);
    o1.y = 10.0f * tanhf(acc[i][5] * 0.03125f);
    o1.z = 10.0f * tanhf(acc[i][6] * 0.03125f);
    o1.w = 10.0f * tanhf(acc[i][7] * 0.03125f);
    float* dst = &T[((size_t)b * NN + row) * NN + tx * 8];
    *(float4*)dst = o0;
    *(float4*)(dst + 4) = o1;
  }
}

// chain-only decode: dependent T-row read + INLINE gumbel (bit-identical to the old
// k_gumbel values: same threefry(keys[s],0,b*128+n) -> same gumbel_from_bits).
// Next step's gumbel ALU (~200 instr) executes under the dependent load's latency.
// Removes the k_gumbel dispatch and 266 MB of G write+read HBM traffic.
__global__ __launch_bounds__(64) void k_decode(
    const float* __restrict__ T, const uint2* __restrict__ keys,
    float* __restrict__ out, int* __restrict__ pos) {
  int b = blockIdx.x;
  int lane = threadIdx.x;
  const int n0 = 2 * lane;
  bool vis0 = (n0 == 0), vis1 = false;
  int cur = 0;
  if (lane == 0) { out[b * NN] = 0.0f; pos[b * NN] = 0; }
  const float* Tb = T + (size_t)b * NN * NN;
  const uint32_t cnt0 = (uint32_t)(b * NN + n0);
  uint2 k0 = keys[0];
  uint2 ra = threefry(k0.x, k0.y, 0u, cnt0);
  uint2 rb = threefry(k0.x, k0.y, 0u, cnt0 + 1u);
  float2 gnext;
  gnext.x = gumbel_from_bits(ra.x ^ ra.y);
  gnext.y = gumbel_from_bits(rb.x ^ rb.y);
  for (int s = 0; s < NN - 1; ++s) {
    float2 gc = gnext;
    float2 sc = *(const float2*)&Tb[cur * NN + n0];     // dependent load (issue first)
    if (s + 1 < NN - 1) {                               // independent ALU hides under it
      uint2 kk = keys[s + 1];
      uint2 qa = threefry(kk.x, kk.y, 0u, cnt0);
      uint2 qb = threefry(kk.x, kk.y, 0u, cnt0 + 1u);
      gnext.x = gumbel_from_bits(qa.x ^ qa.y);
      gnext.y = gumbel_from_bits(qb.x ^ qb.y);
    }
    float v0 = vis0 ? -INFINITY : sc.x + gc.x;
    float v1 = vis1 ? -INFINITY : sc.y + gc.y;
    float bvv; int bi;
    if (v1 > v0) { bvv = v1; bi = n0 + 1; } else { bvv = v0; bi = n0; }
#pragma unroll
    for (int off = 32; off > 0; off >>= 1) {
      float ov = __shfl_xor(bvv, off);
      int oi = __shfl_xor(bi, off);
      if (ov > bvv || (ov == bvv && oi < bi)) { bvv = ov; bi = oi; }
    }
    cur = bi;
    vis0 = vis0 || (n0 == cur);
    vis1 = vis1 || (n0 + 1 == cur);
    if (lane == 0) { out[b * NN + s + 1] = (float)cur; pos[b * NN + cur] = s + 1; }
  }
}

// logp: block per b (4 waves). order[] from pos scatter in LDS; wave w owns steps
// s = w, w+4, ... Row loads are independent (addr from LDS), pipelined one ahead.
__global__ __launch_bounds__(256) void k_logp(
    const float* __restrict__ T, const int* __restrict__ pos,
    float* __restrict__ out) {
  __shared__ int order[NN];
  __shared__ int poss[NN];
  __shared__ float parts[NN];
  int b = blockIdx.x, tid = threadIdx.x;
  if (tid < NN) {
    int p = pos[b * NN + tid];
    poss[tid] = p;
    order[p] = tid;
  }
  __syncthreads();
  int w = tid >> 6, lane = tid & 63;
  const float* Tb = T + (size_t)b * NN * NN;
  int p0 = poss[lane], p1 = poss[lane + 64];
  int s = w;
  int r = order[s];
  float sc0 = Tb[r * NN + lane];
  float sc1 = Tb[r * NN + lane + 64];
  float scn = Tb[r * NN + order[s + 1]];     // uniform broadcast load
  while (true) {
    int s2 = s + 4;
    bool more = (s2 < NN - 1);
    float nsc0 = 0.f, nsc1 = 0.f, nscn = 0.f;
    if (more) {                              // prefetch next step's row (independent)
      int r2 = order[s2];
      nsc0 = Tb[r2 * NN + lane];
      nsc1 = Tb[r2 * NN + lane + 64];
      nscn = Tb[r2 * NN + order[s2 + 1]];
    }
    bool u0 = (p0 > s), u1 = (p1 > s);       // unvisited at step s
    float m = fmaxf(u0 ? sc0 : -INFINITY, u1 ? sc1 : -INFINITY);
#pragma unroll
    for (int off = 32; off > 0; off >>= 1) m = fmaxf(m, __shfl_xor(m, off));
    float e = (u0 ? expf(sc0 - m) : 0.f) + (u1 ? expf(sc1 - m) : 0.f);
#pragma unroll
    for (int off = 32; off > 0; off >>= 1) e += __shfl_xor(e, off);
    if (lane == 0) parts[s] = scn - m - logf(e);
    if (!more) break;
    s = s2; sc0 = nsc0; sc1 = nsc1; scn = nscn;
  }
  __syncthreads();
  if (tid == 0) {
    float acc = 0.f;
    for (int i = 0; i < NN - 1; ++i) acc += parts[i];   // ascending s: deterministic
    out[BB * NN + b] = acc;
  }
}

extern "C" void kernel_launch(void* const* d_in, const int* in_sizes, int n_in,
                              void* d_out, int out_size, void* d_ws, size_t ws_size,
                              hipStream_t stream) {
  const float* h     = (const float*)d_in[0];
  const float* graph = (const float*)d_in[1];
  const float* Wq    = (const float*)d_in[2];
  const float* bq    = (const float*)d_in[3];
  const float* Wk    = (const float*)d_in[4];
  const float* bk    = (const float*)d_in[5];
  const float* Wc    = (const float*)d_in[8];
  const float* bc    = (const float*)d_in[9];
  float* out = (float*)d_out;

  char* ws = (char*)d_ws;
  uint2* keys  = (uint2*)ws;                        // 1 KB
  float* Mm    = (float*)(ws + 1024);               // 64 KB
  float* Qbase = (float*)(ws + 66560);              // 1 MB
  int*   pos   = (int*)  (ws + 1115136);            // 1 MB
  float* T     = (float*)(ws + (size_t)(4 << 20));  // 134.2 MB
  // X region: Kc/QQc during the chunk loop (G eliminated — gumbel is inline in decode).
  size_t xoff  = (size_t)(4 << 20) + (size_t)BB * NN * NN * 4;
  float* Kc    = (float*)(ws + xoff);                                   // 67.1 MB
  float* QQc   = (float*)(ws + xoff + (size_t)CHUNK * NN * DD * 4);     // 67.1 MB

  k_keys<<<1, 128, 0, stream>>>(keys);
  k_M<<<128, 128, 0, stream>>>(Wc, Wq, Mm);
  k_qbase<<<BB, 128, 0, stream>>>(graph, Wc, bc, Wq, bq, Qbase);
  for (int b0 = 0; b0 < BB; b0 += CHUNK) {
    k_kqq<<<CHUNK * NN / 64, 512, 0, stream>>>(h, Wk, bk, Mm, Qbase, Kc, QQc, b0);
    k_score<<<CHUNK, 512, 0, stream>>>(QQc, Kc, T, b0);
  }
  k_decode<<<BB, 64, 0, stream>>>(T, keys, out, pos);
  k_logp<<<BB, 256, 0, stream>>>(T, pos, out);
}

// Round 3
// 1253.461 us; speedup vs baseline: 1.9962x; 1.9962x over previous
//
#include <hip/hip_runtime.h>
#include <cstdint>

#define BB 2048
#define NN 128
#define DD 128
#define CHUNK 1024
#define SW 36

// ---------------- threefry2x32 (JAX-exact) ----------------
__device__ __forceinline__ void tf_round(uint32_t& x0, uint32_t& x1, int r) {
  x0 += x1; x1 = (x1 << r) | (x1 >> (32 - r)); x1 ^= x0;
}

__device__ __forceinline__ uint2 threefry(uint32_t k0, uint32_t k1, uint32_t x0, uint32_t x1) {
  uint32_t k2 = k0 ^ k1 ^ 0x1BD11BDAu;
  x0 += k0; x1 += k1;
  tf_round(x0,x1,13); tf_round(x0,x1,15); tf_round(x0,x1,26); tf_round(x0,x1,6);
  x0 += k1; x1 += k2 + 1u;
  tf_round(x0,x1,17); tf_round(x0,x1,29); tf_round(x0,x1,16); tf_round(x0,x1,24);
  x0 += k2; x1 += k0 + 2u;
  tf_round(x0,x1,13); tf_round(x0,x1,15); tf_round(x0,x1,26); tf_round(x0,x1,6);
  x0 += k0; x1 += k1 + 3u;
  tf_round(x0,x1,17); tf_round(x0,x1,29); tf_round(x0,x1,16); tf_round(x0,x1,24);
  x0 += k1; x1 += k2 + 4u;
  tf_round(x0,x1,13); tf_round(x0,x1,15); tf_round(x0,x1,26); tf_round(x0,x1,6);
  x0 += k2; x1 += k0 + 5u;
  uint2 r; r.x = x0; r.y = x1; return r;
}

__device__ __forceinline__ float gumbel_from_bits(uint32_t bits) {
  const float TINY = 1.17549435e-38f;
  float u = __uint_as_float(0x3F800000u | (bits >> 9)) - 1.0f;   // [0,1)
  u = u + TINY;
  u = fmaxf(TINY, u);
  return -logf(-logf(u));   // libm logf: sampling-critical, do not weaken
}

// keys[i] = threefry((0,42),(0,i))
__global__ void k_keys(uint2* __restrict__ keys) {
  int i = threadIdx.x;
  if (i < NN) keys[i] = threefry(0u, 42u, 0u, (uint32_t)i);
}

// M = Wc2 @ Wq   (Wc rows 128..255 are the h_cur part)
__global__ void k_M(const float* __restrict__ Wc, const float* __restrict__ Wq,
                    float* __restrict__ M) {
  __shared__ __align__(16) float wrow[DD];
  int r = blockIdx.x, o = threadIdx.x;
  wrow[o] = Wc[(DD + r) * DD + o];
  __syncthreads();
  float acc = 0.f;
#pragma unroll 4
  for (int c = 0; c < DD; ++c) acc += wrow[c] * Wq[c * DD + o];
  M[r * DD + o] = acc;
}

// Qbase[b] = (graph[b]@Wc1 + bc) @ Wq + bq
__global__ void k_qbase(const float* __restrict__ graph, const float* __restrict__ Wc,
                        const float* __restrict__ bc, const float* __restrict__ Wq,
                        const float* __restrict__ bq, float* __restrict__ Qbase) {
  __shared__ __align__(16) float g[DD];
  __shared__ __align__(16) float c1[DD];
  int b = blockIdx.x, t = threadIdx.x;
  g[t] = graph[b * DD + t];
  __syncthreads();
  float acc = 0.f;
#pragma unroll 4
  for (int r = 0; r < DD; ++r) acc += g[r] * Wc[r * DD + t];
  c1[t] = acc + bc[t];
  __syncthreads();
  float acc2 = 0.f;
#pragma unroll 4
  for (int c = 0; c < DD; ++c) acc2 += c1[c] * Wq[c * DD + t];
  Qbase[b * DD + t] = acc2 + bq[t];
}

// K = h@Wk + bk ; QQ = h@M + Qbase[b]
// 64 rows/block, 512 threads, 4 rows x 4 cols x 2 mats per thread (32 acc).
// __launch_bounds__(512, 2): R1's (512,4) resolved to a 64-VGPR cap on this
// toolchain -> scratch spills (FETCH 14x, WRITE 26x). Cap 256 lets the natural
// ~110-reg allocation stand -> 128-granule -> 4 waves/SIMD, no spill.
// Per-element accumulation order over (kp,k4,kk) IDENTICAL to prior version.
__global__ __launch_bounds__(512, 2) void k_kqq(
    const float* __restrict__ h, const float* __restrict__ Wk, const float* __restrict__ bk,
    const float* __restrict__ Mm, const float* __restrict__ Qbase,
    float* __restrict__ Kc, float* __restrict__ QQc, int b0) {
  __shared__ __align__(16) float As[64 * 32];    // 8 KB, swizzled
  __shared__ __align__(16) float Wks[32 * DD];   // 16 KB
  __shared__ __align__(16) float Mms[32 * DD];   // 16 KB
  int tid = threadIdx.x;
  int grow0 = b0 * NN + blockIdx.x * 64;  // global flat row (b*N+n)
  int ty = tid >> 5, tx = tid & 31;       // ty 0..15 (4 rows each), tx 0..31 (4 cols each)
  float accK[4][4] = {{0}}, accQ[4][4] = {{0}};
  for (int kp = 0; kp < DD; kp += 32) {
    __syncthreads();
    {                                                 // h panel 64x32 (1 float4/thread)
      int r = tid >> 3, c4 = (tid & 7) * 4;
      int pc = c4 ^ ((r & 7) * 4);
      *(float4*)&As[r * 32 + pc] = *(const float4*)&h[(size_t)(grow0 + r) * DD + kp + c4];
    }
#pragma unroll
    for (int p = 0; p < 2; ++p) {                     // weight panels 32x128
      int t = tid + p * 512;
      int r = t >> 5, c4 = (t & 31) * 4;
      *(float4*)&Wks[r * DD + c4] = *(const float4*)&Wk[(size_t)(kp + r) * DD + c4];
      *(float4*)&Mms[r * DD + c4] = *(const float4*)&Mm[(size_t)(kp + r) * DD + c4];
    }
    __syncthreads();
#pragma unroll
    for (int k4 = 0; k4 < 32; k4 += 4) {
      float4 a4[4];
#pragma unroll
      for (int i = 0; i < 4; ++i) {
        int row = ty * 4 + i;
        a4[i] = *(const float4*)&As[row * 32 + (k4 ^ ((row & 7) * 4))];
      }
#pragma unroll
      for (int kk = 0; kk < 4; ++kk) {
        float4 w = *(const float4*)&Wks[(k4 + kk) * DD + tx * 4];
        float4 m = *(const float4*)&Mms[(k4 + kk) * DD + tx * 4];
#pragma unroll
        for (int i = 0; i < 4; ++i) {
          float a = ((const float*)&a4[i])[kk];
          accK[i][0] += a * w.x; accK[i][1] += a * w.y; accK[i][2] += a * w.z; accK[i][3] += a * w.w;
          accQ[i][0] += a * m.x; accQ[i][1] += a * m.y; accQ[i][2] += a * m.z; accQ[i][3] += a * m.w;
        }
      }
    }
  }
  float4 bk4 = *(const float4*)&bk[tx * 4];
#pragma unroll
  for (int i = 0; i < 4; ++i) {
    int grow = grow0 + ty * 4 + i;
    int b = grow >> 7;
    int lrow = grow - b0 * NN;
    float4 qb = *(const float4*)&Qbase[b * DD + tx * 4];
    float4 ok, oq;
    ok.x = accK[i][0] + bk4.x; ok.y = accK[i][1] + bk4.y;
    ok.z = accK[i][2] + bk4.z; ok.w = accK[i][3] + bk4.w;
    oq.x = accQ[i][0] + qb.x;  oq.y = accQ[i][1] + qb.y;
    oq.z = accQ[i][2] + qb.z;  oq.w = accQ[i][3] + qb.w;
    *(float4*)&Kc[lrow * DD + tx * 4] = ok;
    *(float4*)&QQc[lrow * DD + tx * 4] = oq;
  }
}

// T[b] = 10*tanh( QQ[b] @ K[b]^T / 32 )
// 512 threads, 4x8 per thread (32 acc). __launch_bounds__(512, 2): see k_kqq —
// R1's (512,4) forced a 64-VGPR cap and spilled ~2 GB/dispatch to scratch.
// Same 128x128 block tile, same LDS swizzle; per-element FMA order identical (bit-exact).
__global__ __launch_bounds__(512, 2) void k_score(
    const float* __restrict__ QQc, const float* __restrict__ Kc,
    float* __restrict__ T, int b0) {
  __shared__ __align__(16) float QQs[NN * SW];
  __shared__ __align__(16) float Ks[NN * SW];
  int bb = blockIdx.x;
  int tid = threadIdx.x;
  int ty = tid >> 4, tx = tid & 15;     // ty 0..31 (4 rows each), tx 0..15 (8 cols each)
  const float* QQb = QQc + (size_t)bb * NN * DD;
  const float* Kb  = Kc  + (size_t)bb * NN * DD;
  float acc[4][8] = {{0}};
  for (int kp = 0; kp < DD; kp += 32) {
#pragma unroll
    for (int p = 0; p < 2; ++p) {
      int idx = tid + p * 512;
      int row = idx >> 3, c4 = (idx & 7) * 4;
      int pc = c4 ^ (((row >> 3) & 7) * 4);
      *(float4*)&QQs[row * SW + pc] = *(const float4*)&QQb[row * DD + kp + c4];
      *(float4*)&Ks [row * SW + pc] = *(const float4*)&Kb [row * DD + kp + c4];
    }
    __syncthreads();
#pragma unroll
    for (int k4 = 0; k4 < 32; k4 += 4) {
      int ca = k4 ^ (((ty >> 1) & 7) * 4);
      int cb = k4 ^ ((tx & 7) * 4);
      float4 a[4], bv[8];
#pragma unroll
      for (int i = 0; i < 4; ++i) a[i]  = *(const float4*)&QQs[(ty * 4 + i) * SW + ca];
#pragma unroll
      for (int j = 0; j < 8; ++j) bv[j] = *(const float4*)&Ks [(tx * 8 + j) * SW + cb];
#pragma unroll
      for (int i = 0; i < 4; ++i)
#pragma unroll
        for (int j = 0; j < 8; ++j)
          acc[i][j] += a[i].x * bv[j].x + a[i].y * bv[j].y +
                       a[i].z * bv[j].z + a[i].w * bv[j].w;
    }
    __syncthreads();
  }
  int b = b0 + bb;
#pragma unroll
  for (int i = 0; i < 4; ++i) {
    int row = ty * 4 + i;
    float4 o0, o1;
    o0.x = 10.0f * tanhf(acc[i][0] * 0.03125f);
    o0.y = 10.0f * tanhf(acc[i][1] * 0.03125f);
    o0.z = 10.0f * tanhf(acc[i][2] * 0.03125f);
    o0.w = 10.0f * tanhf(acc[i][3] * 0.03125f);
    o1.x = 10.0f * tanhf(acc[i][4] * 0.03125f);
    o1.y = 10.0f * tanhf(acc[i][5] * 0.03125f);
    o1.z = 10.0f * tanhf(acc[i][6] * 0.03125f);
    o1.w = 10.0f * tanhf(acc[i][7] * 0.03125f);
    float* dst = &T[((size_t)b * NN + row) * NN + tx * 8];
    *(float4*)dst = o0;
    *(float4*)(dst + 4) = o1;
  }
}

// chain-only decode: dependent T-row read + INLINE gumbel (bit-identical to the old
// k_gumbel values: same threefry(keys[s],0,b*128+n) -> same gumbel_from_bits).
// Next step's gumbel ALU (~200 instr) executes under the dependent load's latency.
__global__ __launch_bounds__(64) void k_decode(
    const float* __restrict__ T, const uint2* __restrict__ keys,
    float* __restrict__ out, int* __restrict__ pos) {
  int b = blockIdx.x;
  int lane = threadIdx.x;
  const int n0 = 2 * lane;
  bool vis0 = (n0 == 0), vis1 = false;
  int cur = 0;
  if (lane == 0) { out[b * NN] = 0.0f; pos[b * NN] = 0; }
  const float* Tb = T + (size_t)b * NN * NN;
  const uint32_t cnt0 = (uint32_t)(b * NN + n0);
  uint2 k0 = keys[0];
  uint2 ra = threefry(k0.x, k0.y, 0u, cnt0);
  uint2 rb = threefry(k0.x, k0.y, 0u, cnt0 + 1u);
  float2 gnext;
  gnext.x = gumbel_from_bits(ra.x ^ ra.y);
  gnext.y = gumbel_from_bits(rb.x ^ rb.y);
  for (int s = 0; s < NN - 1; ++s) {
    float2 gc = gnext;
    float2 sc = *(const float2*)&Tb[cur * NN + n0];     // dependent load (issue first)
    if (s + 1 < NN - 1) {                               // independent ALU hides under it
      uint2 kk = keys[s + 1];
      uint2 qa = threefry(kk.x, kk.y, 0u, cnt0);
      uint2 qb = threefry(kk.x, kk.y, 0u, cnt0 + 1u);
      gnext.x = gumbel_from_bits(qa.x ^ qa.y);
      gnext.y = gumbel_from_bits(qb.x ^ qb.y);
    }
    float v0 = vis0 ? -INFINITY : sc.x + gc.x;
    float v1 = vis1 ? -INFINITY : sc.y + gc.y;
    float bvv; int bi;
    if (v1 > v0) { bvv = v1; bi = n0 + 1; } else { bvv = v0; bi = n0; }
#pragma unroll
    for (int off = 32; off > 0; off >>= 1) {
      float ov = __shfl_xor(bvv, off);
      int oi = __shfl_xor(bi, off);
      if (ov > bvv || (ov == bvv && oi < bi)) { bvv = ov; bi = oi; }
    }
    cur = bi;
    vis0 = vis0 || (n0 == cur);
    vis1 = vis1 || (n0 + 1 == cur);
    if (lane == 0) { out[b * NN + s + 1] = (float)cur; pos[b * NN + cur] = s + 1; }
  }
}

// logp: block per b (4 waves). order[] from pos scatter in LDS; wave w owns steps
// s = w, w+4, ... Row loads are independent (addr from LDS), pipelined one ahead.
__global__ __launch_bounds__(256) void k_logp(
    const float* __restrict__ T, const int* __restrict__ pos,
    float* __restrict__ out) {
  __shared__ int order[NN];
  __shared__ int poss[NN];
  __shared__ float parts[NN];
  int b = blockIdx.x, tid = threadIdx.x;
  if (tid < NN) {
    int p = pos[b * NN + tid];
    poss[tid] = p;
    order[p] = tid;
  }
  __syncthreads();
  int w = tid >> 6, lane = tid & 63;
  const float* Tb = T + (size_t)b * NN * NN;
  int p0 = poss[lane], p1 = poss[lane + 64];
  int s = w;
  int r = order[s];
  float sc0 = Tb[r * NN + lane];
  float sc1 = Tb[r * NN + lane + 64];
  float scn = Tb[r * NN + order[s + 1]];     // uniform broadcast load
  while (true) {
    int s2 = s + 4;
    bool more = (s2 < NN - 1);
    float nsc0 = 0.f, nsc1 = 0.f, nscn = 0.f;
    if (more) {                              // prefetch next step's row (independent)
      int r2 = order[s2];
      nsc0 = Tb[r2 * NN + lane];
      nsc1 = Tb[r2 * NN + lane + 64];
      nscn = Tb[r2 * NN + order[s2 + 1]];
    }
    bool u0 = (p0 > s), u1 = (p1 > s);       // unvisited at step s
    float m = fmaxf(u0 ? sc0 : -INFINITY, u1 ? sc1 : -INFINITY);
#pragma unroll
    for (int off = 32; off > 0; off >>= 1) m = fmaxf(m, __shfl_xor(m, off));
    float e = (u0 ? expf(sc0 - m) : 0.f) + (u1 ? expf(sc1 - m) : 0.f);
#pragma unroll
    for (int off = 32; off > 0; off >>= 1) e += __shfl_xor(e, off);
    if (lane == 0) parts[s] = scn - m - logf(e);
    if (!more) break;
    s = s2; sc0 = nsc0; sc1 = nsc1; scn = nscn;
  }
  __syncthreads();
  if (tid == 0) {
    float acc = 0.f;
    for (int i = 0; i < NN - 1; ++i) acc += parts[i];   // ascending s: deterministic
    out[BB * NN + b] = acc;
  }
}

extern "C" void kernel_launch(void* const* d_in, const int* in_sizes, int n_in,
                              void* d_out, int out_size, void* d_ws, size_t ws_size,
                              hipStream_t stream) {
  const float* h     = (const float*)d_in[0];
  const float* graph = (const float*)d_in[1];
  const float* Wq    = (const float*)d_in[2];
  const float* bq    = (const float*)d_in[3];
  const float* Wk    = (const float*)d_in[4];
  const float* bk    = (const float*)d_in[5];
  const float* Wc    = (const float*)d_in[8];
  const float* bc    = (const float*)d_in[9];
  float* out = (float*)d_out;

  char* ws = (char*)d_ws;
  uint2* keys  = (uint2*)ws;                        // 1 KB
  float* Mm    = (float*)(ws + 1024);               // 64 KB
  float* Qbase = (float*)(ws + 66560);              // 1 MB
  int*   pos   = (int*)  (ws + 1115136);            // 1 MB
  float* T     = (float*)(ws + (size_t)(4 << 20));  // 134.2 MB
  // X region: Kc/QQc during the chunk loop (G eliminated — gumbel is inline in decode).
  size_t xoff  = (size_t)(4 << 20) + (size_t)BB * NN * NN * 4;
  float* Kc    = (float*)(ws + xoff);                                   // 67.1 MB
  float* QQc   = (float*)(ws + xoff + (size_t)CHUNK * NN * DD * 4);     // 67.1 MB

  k_keys<<<1, 128, 0, stream>>>(keys);
  k_M<<<128, 128, 0, stream>>>(Wc, Wq, Mm);
  k_qbase<<<BB, 128, 0, stream>>>(graph, Wc, bc, Wq, bq, Qbase);
  for (int b0 = 0; b0 < BB; b0 += CHUNK) {
    k_kqq<<<CHUNK * NN / 64, 512, 0, stream>>>(h, Wk, bk, Mm, Qbase, Kc, QQc, b0);
    k_score<<<CHUNK, 512, 0, stream>>>(QQc, Kc, T, b0);
  }
  k_decode<<<BB, 64, 0, stream>>>(T, keys, out, pos);
  k_logp<<<BB, 256, 0, stream>>>(T, pos, out);
}

// Round 4
// 829.924 us; speedup vs baseline: 3.0150x; 1.5103x over previous
//
#include <hip/hip_runtime.h>
#include <cstdint>

#define BB 2048
#define NN 128
#define DD 128
#define CHUNK 1024
#define SW 36

// ---------------- threefry2x32 (JAX-exact) ----------------
__device__ __forceinline__ void tf_round(uint32_t& x0, uint32_t& x1, int r) {
  x0 += x1; x1 = (x1 << r) | (x1 >> (32 - r)); x1 ^= x0;
}

__device__ __forceinline__ uint2 threefry(uint32_t k0, uint32_t k1, uint32_t x0, uint32_t x1) {
  uint32_t k2 = k0 ^ k1 ^ 0x1BD11BDAu;
  x0 += k0; x1 += k1;
  tf_round(x0,x1,13); tf_round(x0,x1,15); tf_round(x0,x1,26); tf_round(x0,x1,6);
  x0 += k1; x1 += k2 + 1u;
  tf_round(x0,x1,17); tf_round(x0,x1,29); tf_round(x0,x1,16); tf_round(x0,x1,24);
  x0 += k2; x1 += k0 + 2u;
  tf_round(x0,x1,13); tf_round(x0,x1,15); tf_round(x0,x1,26); tf_round(x0,x1,6);
  x0 += k0; x1 += k1 + 3u;
  tf_round(x0,x1,17); tf_round(x0,x1,29); tf_round(x0,x1,16); tf_round(x0,x1,24);
  x0 += k1; x1 += k2 + 4u;
  tf_round(x0,x1,13); tf_round(x0,x1,15); tf_round(x0,x1,26); tf_round(x0,x1,6);
  x0 += k2; x1 += k0 + 5u;
  uint2 r; r.x = x0; r.y = x1; return r;
}

__device__ __forceinline__ float gumbel_from_bits(uint32_t bits) {
  const float TINY = 1.17549435e-38f;
  float u = __uint_as_float(0x3F800000u | (bits >> 9)) - 1.0f;   // [0,1)
  u = u + TINY;
  u = fmaxf(TINY, u);
  return -logf(-logf(u));   // libm logf: sampling-critical, do not weaken
}

// keys[i] = threefry((0,42),(0,i))
__global__ void k_keys(uint2* __restrict__ keys) {
  int i = threadIdx.x;
  if (i < NN) keys[i] = threefry(0u, 42u, 0u, (uint32_t)i);
}

// M = Wc2 @ Wq   (Wc rows 128..255 are the h_cur part)
__global__ void k_M(const float* __restrict__ Wc, const float* __restrict__ Wq,
                    float* __restrict__ M) {
  __shared__ __align__(16) float wrow[DD];
  int r = blockIdx.x, o = threadIdx.x;
  wrow[o] = Wc[(DD + r) * DD + o];
  __syncthreads();
  float acc = 0.f;
#pragma unroll 4
  for (int c = 0; c < DD; ++c) acc += wrow[c] * Wq[c * DD + o];
  M[r * DD + o] = acc;
}

// Qbase[b] = (graph[b]@Wc1 + bc) @ Wq + bq
__global__ void k_qbase(const float* __restrict__ graph, const float* __restrict__ Wc,
                        const float* __restrict__ bc, const float* __restrict__ Wq,
                        const float* __restrict__ bq, float* __restrict__ Qbase) {
  __shared__ __align__(16) float g[DD];
  __shared__ __align__(16) float c1[DD];
  int b = blockIdx.x, t = threadIdx.x;
  g[t] = graph[b * DD + t];
  __syncthreads();
  float acc = 0.f;
#pragma unroll 4
  for (int r = 0; r < DD; ++r) acc += g[r] * Wc[r * DD + t];
  c1[t] = acc + bc[t];
  __syncthreads();
  float acc2 = 0.f;
#pragma unroll 4
  for (int c = 0; c < DD; ++c) acc2 += c1[c] * Wq[c * DD + t];
  Qbase[b * DD + t] = acc2 + bq[t];
}

// K = h@Wk + bk ; QQ = h@M + Qbase[b]
// 64 rows/block, 512 threads, 4 rows x 4 cols x 2 mats per thread (32 acc).
// (512,2) -> 128-VGPR cap, 4 waves/SIMD. Not spilling (live set ~90).
// Per-element accumulation order over (kp,k4,kk) IDENTICAL to prior version.
__global__ __launch_bounds__(512, 2) void k_kqq(
    const float* __restrict__ h, const float* __restrict__ Wk, const float* __restrict__ bk,
    const float* __restrict__ Mm, const float* __restrict__ Qbase,
    float* __restrict__ Kc, float* __restrict__ QQc, int b0) {
  __shared__ __align__(16) float As[64 * 32];    // 8 KB, swizzled
  __shared__ __align__(16) float Wks[32 * DD];   // 16 KB
  __shared__ __align__(16) float Mms[32 * DD];   // 16 KB
  int tid = threadIdx.x;
  int grow0 = b0 * NN + blockIdx.x * 64;  // global flat row (b*N+n)
  int ty = tid >> 5, tx = tid & 31;       // ty 0..15 (4 rows each), tx 0..31 (4 cols each)
  float accK[4][4] = {{0}}, accQ[4][4] = {{0}};
  for (int kp = 0; kp < DD; kp += 32) {
    __syncthreads();
    {                                                 // h panel 64x32 (1 float4/thread)
      int r = tid >> 3, c4 = (tid & 7) * 4;
      int pc = c4 ^ ((r & 7) * 4);
      *(float4*)&As[r * 32 + pc] = *(const float4*)&h[(size_t)(grow0 + r) * DD + kp + c4];
    }
#pragma unroll
    for (int p = 0; p < 2; ++p) {                     // weight panels 32x128
      int t = tid + p * 512;
      int r = t >> 5, c4 = (t & 31) * 4;
      *(float4*)&Wks[r * DD + c4] = *(const float4*)&Wk[(size_t)(kp + r) * DD + c4];
      *(float4*)&Mms[r * DD + c4] = *(const float4*)&Mm[(size_t)(kp + r) * DD + c4];
    }
    __syncthreads();
#pragma unroll
    for (int k4 = 0; k4 < 32; k4 += 4) {
      float4 a4[4];
#pragma unroll
      for (int i = 0; i < 4; ++i) {
        int row = ty * 4 + i;
        a4[i] = *(const float4*)&As[row * 32 + (k4 ^ ((row & 7) * 4))];
      }
#pragma unroll
      for (int kk = 0; kk < 4; ++kk) {
        float4 w = *(const float4*)&Wks[(k4 + kk) * DD + tx * 4];
        float4 m = *(const float4*)&Mms[(k4 + kk) * DD + tx * 4];
#pragma unroll
        for (int i = 0; i < 4; ++i) {
          float a = ((const float*)&a4[i])[kk];
          accK[i][0] += a * w.x; accK[i][1] += a * w.y; accK[i][2] += a * w.z; accK[i][3] += a * w.w;
          accQ[i][0] += a * m.x; accQ[i][1] += a * m.y; accQ[i][2] += a * m.z; accQ[i][3] += a * m.w;
        }
      }
    }
  }
  float4 bk4 = *(const float4*)&bk[tx * 4];
#pragma unroll
  for (int i = 0; i < 4; ++i) {
    int grow = grow0 + ty * 4 + i;
    int b = grow >> 7;
    int lrow = grow - b0 * NN;
    float4 qb = *(const float4*)&Qbase[b * DD + tx * 4];
    float4 ok, oq;
    ok.x = accK[i][0] + bk4.x; ok.y = accK[i][1] + bk4.y;
    ok.z = accK[i][2] + bk4.z; ok.w = accK[i][3] + bk4.w;
    oq.x = accQ[i][0] + qb.x;  oq.y = accQ[i][1] + qb.y;
    oq.z = accQ[i][2] + qb.z;  oq.w = accQ[i][3] + qb.w;
    *(float4*)&Kc[lrow * DD + tx * 4] = ok;
    *(float4*)&QQc[lrow * DD + tx * 4] = oq;
  }
}

// T[b] = 10*tanh( QQ[b] @ K[b]^T / 32 )
// 512 threads, 4x8 per thread (32 acc), 128-VGPR cap.
// R3 post-mortem: full k4 unroll + 8-wide bv live set spilled ~900 MB/dispatch
// to scratch (FETCH 421 MB, WRITE 680 MB). Fix: (1) bv split into two 4-wide
// scoped groups (live ~92 regs), (2) k4 unroll limited to 2 to shrink the
// scheduler hoisting window. Per-accumulator FMA chain over (kp,k4,kk) is
// UNCHANGED (j-grouping only reorders between independent accumulators).
__global__ __launch_bounds__(512, 2) void k_score(
    const float* __restrict__ QQc, const float* __restrict__ Kc,
    float* __restrict__ T, int b0) {
  __shared__ __align__(16) float QQs[NN * SW];
  __shared__ __align__(16) float Ks[NN * SW];
  int bb = blockIdx.x;
  int tid = threadIdx.x;
  int ty = tid >> 4, tx = tid & 15;     // ty 0..31 (4 rows each), tx 0..15 (8 cols each)
  const float* QQb = QQc + (size_t)bb * NN * DD;
  const float* Kb  = Kc  + (size_t)bb * NN * DD;
  float acc[4][8] = {{0}};
  for (int kp = 0; kp < DD; kp += 32) {
#pragma unroll
    for (int p = 0; p < 2; ++p) {
      int idx = tid + p * 512;
      int row = idx >> 3, c4 = (idx & 7) * 4;
      int pc = c4 ^ (((row >> 3) & 7) * 4);
      *(float4*)&QQs[row * SW + pc] = *(const float4*)&QQb[row * DD + kp + c4];
      *(float4*)&Ks [row * SW + pc] = *(const float4*)&Kb [row * DD + kp + c4];
    }
    __syncthreads();
#pragma unroll 2
    for (int k4 = 0; k4 < 32; k4 += 4) {
      int ca = k4 ^ (((ty >> 1) & 7) * 4);
      int cb = k4 ^ ((tx & 7) * 4);
      float4 a[4];
#pragma unroll
      for (int i = 0; i < 4; ++i) a[i] = *(const float4*)&QQs[(ty * 4 + i) * SW + ca];
      {                                    // j-group 0..3 (bv live = 4 float4)
        float4 bv[4];
#pragma unroll
        for (int j = 0; j < 4; ++j) bv[j] = *(const float4*)&Ks[(tx * 8 + j) * SW + cb];
#pragma unroll
        for (int i = 0; i < 4; ++i)
#pragma unroll
          for (int j = 0; j < 4; ++j)
            acc[i][j] += a[i].x * bv[j].x + a[i].y * bv[j].y +
                         a[i].z * bv[j].z + a[i].w * bv[j].w;
      }
      {                                    // j-group 4..7
        float4 bv[4];
#pragma unroll
        for (int j = 0; j < 4; ++j) bv[j] = *(const float4*)&Ks[(tx * 8 + 4 + j) * SW + cb];
#pragma unroll
        for (int i = 0; i < 4; ++i)
#pragma unroll
          for (int j = 0; j < 4; ++j)
            acc[i][4 + j] += a[i].x * bv[j].x + a[i].y * bv[j].y +
                             a[i].z * bv[j].z + a[i].w * bv[j].w;
      }
    }
    __syncthreads();
  }
  int b = b0 + bb;
#pragma unroll
  for (int i = 0; i < 4; ++i) {
    int row = ty * 4 + i;
    float4 o0, o1;
    o0.x = 10.0f * tanhf(acc[i][0] * 0.03125f);
    o0.y = 10.0f * tanhf(acc[i][1] * 0.03125f);
    o0.z = 10.0f * tanhf(acc[i][2] * 0.03125f);
    o0.w = 10.0f * tanhf(acc[i][3] * 0.03125f);
    o1.x = 10.0f * tanhf(acc[i][4] * 0.03125f);
    o1.y = 10.0f * tanhf(acc[i][5] * 0.03125f);
    o1.z = 10.0f * tanhf(acc[i][6] * 0.03125f);
    o1.w = 10.0f * tanhf(acc[i][7] * 0.03125f);
    float* dst = &T[((size_t)b * NN + row) * NN + tx * 8];
    *(float4*)dst = o0;
    *(float4*)(dst + 4) = o1;
  }
}

// chain-only decode: dependent T-row read + INLINE gumbel (bit-identical to the old
// k_gumbel values: same threefry(keys[s],0,b*128+n) -> same gumbel_from_bits).
// Next step's gumbel ALU (~200 instr) executes under the dependent load's latency.
__global__ __launch_bounds__(64) void k_decode(
    const float* __restrict__ T, const uint2* __restrict__ keys,
    float* __restrict__ out, int* __restrict__ pos) {
  int b = blockIdx.x;
  int lane = threadIdx.x;
  const int n0 = 2 * lane;
  bool vis0 = (n0 == 0), vis1 = false;
  int cur = 0;
  if (lane == 0) { out[b * NN] = 0.0f; pos[b * NN] = 0; }
  const float* Tb = T + (size_t)b * NN * NN;
  const uint32_t cnt0 = (uint32_t)(b * NN + n0);
  uint2 k0 = keys[0];
  uint2 ra = threefry(k0.x, k0.y, 0u, cnt0);
  uint2 rb = threefry(k0.x, k0.y, 0u, cnt0 + 1u);
  float2 gnext;
  gnext.x = gumbel_from_bits(ra.x ^ ra.y);
  gnext.y = gumbel_from_bits(rb.x ^ rb.y);
  for (int s = 0; s < NN - 1; ++s) {
    float2 gc = gnext;
    float2 sc = *(const float2*)&Tb[cur * NN + n0];     // dependent load (issue first)
    if (s + 1 < NN - 1) {                               // independent ALU hides under it
      uint2 kk = keys[s + 1];
      uint2 qa = threefry(kk.x, kk.y, 0u, cnt0);
      uint2 qb = threefry(kk.x, kk.y, 0u, cnt0 + 1u);
      gnext.x = gumbel_from_bits(qa.x ^ qa.y);
      gnext.y = gumbel_from_bits(qb.x ^ qb.y);
    }
    float v0 = vis0 ? -INFINITY : sc.x + gc.x;
    float v1 = vis1 ? -INFINITY : sc.y + gc.y;
    float bvv; int bi;
    if (v1 > v0) { bvv = v1; bi = n0 + 1; } else { bvv = v0; bi = n0; }
#pragma unroll
    for (int off = 32; off > 0; off >>= 1) {
      float ov = __shfl_xor(bvv, off);
      int oi = __shfl_xor(bi, off);
      if (ov > bvv || (ov == bvv && oi < bi)) { bvv = ov; bi = oi; }
    }
    cur = bi;
    vis0 = vis0 || (n0 == cur);
    vis1 = vis1 || (n0 + 1 == cur);
    if (lane == 0) { out[b * NN + s + 1] = (float)cur; pos[b * NN + cur] = s + 1; }
  }
}

// logp: block per b (4 waves). order[] from pos scatter in LDS; wave w owns steps
// s = w, w+4, ... Row loads are independent (addr from LDS), pipelined one ahead.
__global__ __launch_bounds__(256) void k_logp(
    const float* __restrict__ T, const int* __restrict__ pos,
    float* __restrict__ out) {
  __shared__ int order[NN];
  __shared__ int poss[NN];
  __shared__ float parts[NN];
  int b = blockIdx.x, tid = threadIdx.x;
  if (tid < NN) {
    int p = pos[b * NN + tid];
    poss[tid] = p;
    order[p] = tid;
  }
  __syncthreads();
  int w = tid >> 6, lane = tid & 63;
  const float* Tb = T + (size_t)b * NN * NN;
  int p0 = poss[lane], p1 = poss[lane + 64];
  int s = w;
  int r = order[s];
  float sc0 = Tb[r * NN + lane];
  float sc1 = Tb[r * NN + lane + 64];
  float scn = Tb[r * NN + order[s + 1]];     // uniform broadcast load
  while (true) {
    int s2 = s + 4;
    bool more = (s2 < NN - 1);
    float nsc0 = 0.f, nsc1 = 0.f, nscn = 0.f;
    if (more) {                              // prefetch next step's row (independent)
      int r2 = order[s2];
      nsc0 = Tb[r2 * NN + lane];
      nsc1 = Tb[r2 * NN + lane + 64];
      nscn = Tb[r2 * NN + order[s2 + 1]];
    }
    bool u0 = (p0 > s), u1 = (p1 > s);       // unvisited at step s
    float m = fmaxf(u0 ? sc0 : -INFINITY, u1 ? sc1 : -INFINITY);
#pragma unroll
    for (int off = 32; off > 0; off >>= 1) m = fmaxf(m, __shfl_xor(m, off));
    float e = (u0 ? expf(sc0 - m) : 0.f) + (u1 ? expf(sc1 - m) : 0.f);
#pragma unroll
    for (int off = 32; off > 0; off >>= 1) e += __shfl_xor(e, off);
    if (lane == 0) parts[s] = scn - m - logf(e);
    if (!more) break;
    s = s2; sc0 = nsc0; sc1 = nsc1; scn = nscn;
  }
  __syncthreads();
  if (tid == 0) {
    float acc = 0.f;
    for (int i = 0; i < NN - 1; ++i) acc += parts[i];   // ascending s: deterministic
    out[BB * NN + b] = acc;
  }
}

extern "C" void kernel_launch(void* const* d_in, const int* in_sizes, int n_in,
                              void* d_out, int out_size, void* d_ws, size_t ws_size,
                              hipStream_t stream) {
  const float* h     = (const float*)d_in[0];
  const float* graph = (const float*)d_in[1];
  const float* Wq    = (const float*)d_in[2];
  const float* bq    = (const float*)d_in[3];
  const float* Wk    = (const float*)d_in[4];
  const float* bk    = (const float*)d_in[5];
  const float* Wc    = (const float*)d_in[8];
  const float* bc    = (const float*)d_in[9];
  float* out = (float*)d_out;

  char* ws = (char*)d_ws;
  uint2* keys  = (uint2*)ws;                        // 1 KB
  float* Mm    = (float*)(ws + 1024);               // 64 KB
  float* Qbase = (float*)(ws + 66560);              // 1 MB
  int*   pos   = (int*)  (ws + 1115136);            // 1 MB
  float* T     = (float*)(ws + (size_t)(4 << 20));  // 134.2 MB
  // X region: Kc/QQc during the chunk loop (G eliminated — gumbel is inline in decode).
  size_t xoff  = (size_t)(4 << 20) + (size_t)BB * NN * NN * 4;
  float* Kc    = (float*)(ws + xoff);                                   // 67.1 MB
  float* QQc   = (float*)(ws + xoff + (size_t)CHUNK * NN * DD * 4);     // 67.1 MB

  k_keys<<<1, 128, 0, stream>>>(keys);
  k_M<<<128, 128, 0, stream>>>(Wc, Wq, Mm);
  k_qbase<<<BB, 128, 0, stream>>>(graph, Wc, bc, Wq, bq, Qbase);
  for (int b0 = 0; b0 < BB; b0 += CHUNK) {
    k_kqq<<<CHUNK * NN / 64, 512, 0, stream>>>(h, Wk, bk, Mm, Qbase, Kc, QQc, b0);
    k_score<<<CHUNK, 512, 0, stream>>>(QQc, Kc, T, b0);
  }
  k_decode<<<BB, 64, 0, stream>>>(T, keys, out, pos);
  k_logp<<<BB, 256, 0, stream>>>(T, pos, out);
}